// Round 10
// baseline (148.226 us; speedup 1.0000x reference)
//
#include <hip/hip_runtime.h>
#include <hip/hip_bf16.h>

// A=8 agents, B=64 envs, S=1024 seq, H=128 hidden.
#define AN 8
#define BN 64
#define SN 1024
#define HN 128

typedef __attribute__((ext_vector_type(8))) short bf16x8;
typedef __attribute__((ext_vector_type(4))) float f32x4;

__device__ __forceinline__ short f2bf(float f) {
    unsigned u = __builtin_bit_cast(unsigned, f);
    return (short)((u + 0x7fffu + ((u >> 16) & 1u)) >> 16);  // RNE
}

__device__ __forceinline__ void gll16(const float* g, void* l) {
    __builtin_amdgcn_global_load_lds(
        (const __attribute__((address_space(1))) void*)g,
        (__attribute__((address_space(3))) void*)l, 16, 0, 0);
}

// Stage strip ST into ring slot ST&3 (4 gll per wave: 2 rnn + 2 obs).
// rnn: 16-B-granule XOR swizzle (c' = c ^ (row&7)) applied on the GLOBAL
// source address (gll dest must be linear, rule #21). Dead rows redirect
// the source to a hot dummy line: instruction always issues (vmcnt count
// stays exact), HBM never touches the real row, and scale=0 zeroes it.
#define STAGE(ST) do {                                                         \
    char* sb_ = &ring[(ST) & 3][0];                                            \
    _Pragma("unroll")                                                          \
    for (int jj_ = 0; jj_ < 2; ++jj_) {                                        \
        const int j_   = 2 * wv + jj_;                                         \
        const int row_ = 2 * j_ + (lane >> 5);                                 \
        const int sg_  = s0base + ((ST) << 4) + row_;                          \
        const int c_   = (lane & 31) ^ (row_ & 7);                             \
        const float* g_ = rnn + ((size_t)sg_ * BN + b) * (AN * HN)             \
                              + a * HN + 4 * c_;                               \
        const float* d_ = rnn + 4 * (lane & 31);                               \
        const float* s_ = ((msk[ST] >> row_) & 1u) ? g_ : d_;                  \
        gll16(s_, sb_ + j_ * 1024);                                            \
    }                                                                          \
    _Pragma("unroll")                                                          \
    for (int mm_ = 0; mm_ < 2; ++mm_) {                                        \
        const int ro_ = mm_ * 8 + (lane >> 3);                                 \
        const int sg_ = s0base + ((ST) << 4) + ro_;                            \
        const float* g_ = obs + iobase + (size_t)sg_ * HN                      \
                              + 32 * wv + 4 * (lane & 7);                      \
        gll16(g_, sb_ + 8192 + wv * 2048 + mm_ * 1024);                        \
    }                                                                          \
} while (0)

// Process strip I. PF = stage statement for strip I+2. WN = exact vmcnt:
// ops issued after STAGE(I) in this wave's queue (gll x4/stage, stores x2).
#define BODY(I, WN, PF) do {                                                   \
    PF;                                                                        \
    asm volatile("s_waitcnt vmcnt(" #WN ")" ::: "memory");                     \
    __builtin_amdgcn_sched_barrier(0);                                         \
    __builtin_amdgcn_s_barrier();                                              \
    const char* sb_ = &ring[(I) & 3][0];                                       \
    const float sc_ = scl[I];                                                  \
    bf16x8 mb_[4];                                                             \
    _Pragma("unroll")                                                          \
    for (int ks_ = 0; ks_ < 4; ++ks_) {                                        \
        const int c0_ = ks_ * 8 + kg * 2;                                      \
        f32x4 lo_ = *(const f32x4*)(sb_ + r * 512 + ((c0_    ) ^ (r & 7)) * 16); \
        f32x4 hi_ = *(const f32x4*)(sb_ + r * 512 + ((c0_ + 1) ^ (r & 7)) * 16); \
        mb_[ks_][0] = f2bf(lo_[0] * sc_); mb_[ks_][1] = f2bf(lo_[1] * sc_);    \
        mb_[ks_][2] = f2bf(lo_[2] * sc_); mb_[ks_][3] = f2bf(lo_[3] * sc_);    \
        mb_[ks_][4] = f2bf(hi_[0] * sc_); mb_[ks_][5] = f2bf(hi_[1] * sc_);    \
        mb_[ks_][6] = f2bf(hi_[2] * sc_); mb_[ks_][7] = f2bf(hi_[3] * sc_);    \
    }                                                                          \
    f32x4 a0_ = (f32x4){0.f, 0.f, 0.f, 0.f};                                   \
    f32x4 a1_ = (f32x4){0.f, 0.f, 0.f, 0.f};                                   \
    _Pragma("unroll")                                                          \
    for (int ks_ = 0; ks_ < 4; ++ks_) {                                        \
        a0_ = __builtin_amdgcn_mfma_f32_16x16x32_bf16(wf[0][ks_], mb_[ks_],    \
                                                      a0_, 0, 0, 0);           \
        a1_ = __builtin_amdgcn_mfma_f32_16x16x32_bf16(wf[1][ks_], mb_[ks_],    \
                                                      a1_, 0, 0, 0);           \
    }                                                                          \
    const float* ol_ = (const float*)(sb_ + 8192 + wv * 2048);                 \
    f32x4 ov0_ = *(const f32x4*)&ol_[(r >> 3) * 256 + ((r & 7) * 8 + kg) * 4]; \
    f32x4 ov1_ = *(const f32x4*)&ol_[(r >> 3) * 256 + ((r & 7) * 8 + 4 + kg) * 4]; \
    const size_t go_ = iobase + (size_t)(s0base + ((I) << 4) + r) * HN         \
                     + 32 * wv + 4 * kg;                                       \
    float4 r0_, r1_;                                                           \
    r0_.x = a0_[0] + bv[0].x + ov0_[0]; r0_.y = a0_[1] + bv[0].y + ov0_[1];    \
    r0_.z = a0_[2] + bv[0].z + ov0_[2]; r0_.w = a0_[3] + bv[0].w + ov0_[3];    \
    r1_.x = a1_[0] + bv[1].x + ov1_[0]; r1_.y = a1_[1] + bv[1].y + ov1_[1];    \
    r1_.z = a1_[2] + bv[1].z + ov1_[2]; r1_.w = a1_[3] + bv[1].w + ov1_[3];    \
    *(float4*)(out + go_)      = r0_;                                          \
    *(float4*)(out + go_ + 16) = r1_;                                          \
} while (0)

__global__ __launch_bounds__(256) void commnet_fused(
    const float* __restrict__ obs,   // (A*B, S, H)
    const float* __restrict__ rnn,   // (S, B, A, H)
    const int*   __restrict__ alive, // (A, B, S, 1)
    const float* __restrict__ W,     // (H, H) [out, in]
    const float* __restrict__ bias,  // (H,)
    float* __restrict__ out)         // (A*B, S, H)
{
    // Ring: 4 slots x 16 KB: [0,8K) rnn strip (16 rows x 512B, swizzled),
    // [8K,16K) obs strip (4 waves x 2KB col-slices). 64 KB total.
    __shared__ char ring[4][16384];

    const int tid  = threadIdx.x;
    const int lane = tid & 63;
    const int wv   = tid >> 6;      // wave owns output cols [32wv, 32wv+32)
    const int r    = lane & 15;     // strip row (s offset) / D msg-row index
    const int kg   = lane >> 4;     // k-group / D out-col group

    const int bid    = blockIdx.x;
    const int ab     = bid >> 2;               // 0..511
    const int a      = ab >> 6;
    const int b      = ab & 63;
    const int s0base = (bid & 3) << 8;         // s-window of 256
    const size_t iobase = (size_t)(a * BN + b) * (SN * HN);

    // W fragments -> registers (A-operand layout, verified R0-R9):
    // lane holds W[16*(2wv+m) + r][32ks + 8kg + j], j=0..7.
    bf16x8 wf[2][4];
#pragma unroll
    for (int m = 0; m < 2; ++m)
#pragma unroll
        for (int ks = 0; ks < 4; ++ks) {
            const float* wp = W + (16 * (2 * wv + m) + r) * HN + 32 * ks + 8 * kg;
            float4 w0 = *(const float4*)wp;
            float4 w1 = *(const float4*)(wp + 4);
            bf16x8 f;
            f[0] = f2bf(w0.x); f[1] = f2bf(w0.y); f[2] = f2bf(w0.z); f[3] = f2bf(w0.w);
            f[4] = f2bf(w1.x); f[5] = f2bf(w1.y); f[6] = f2bf(w1.z); f[7] = f2bf(w1.w);
            wf[m][ks] = f;
        }
    float4 bv[2];
#pragma unroll
    for (int m = 0; m < 2; ++m)
        bv[m] = *(const float4*)(bias + 32 * wv + 16 * m + 4 * kg);

    // alive scales -> scratch (aliased into slot 3; dead before STAGE(3)).
    float* scratch = (float*)&ring[3][0];
    {
        const int sg = s0base + tid;
        int asum = 0, mya = 0;
#pragma unroll
        for (int a2 = 0; a2 < AN; ++a2) {
            int v = alive[(a2 * BN + b) * SN + sg];
            asum += v;
            if (a2 == a) mya = v;
        }
        scratch[tid] = mya ? 1.0f / (float)(asum < 1 ? 1 : asum) : 0.0f;
    }
    __syncthreads();   // prologue only: full drain OK, zeroes vmcnt baseline

    float scl[16];      // scale for this lane's compute row r, per strip
    unsigned msk[16];   // per-strip row-alive bits (bits 0..15)
#pragma unroll
    for (int st = 0; st < 16; ++st) {
        float sv = scratch[st * 16 + r];
        scl[st] = sv;
        msk[st] = (unsigned)__ballot(sv > 0.0f);
    }
    asm volatile("s_waitcnt vmcnt(0)" ::: "memory");  // exact-count baseline
    __builtin_amdgcn_s_barrier();

    // Depth-2 pipeline, ring of 4 (slot i+2 never collides with readers).
    STAGE(0);
    STAGE(1);
    BODY(0,  8,  STAGE(2));
    BODY(1,  10, STAGE(3));
    BODY(2,  12, STAGE(4));
    BODY(3,  12, STAGE(5));
    BODY(4,  12, STAGE(6));
    BODY(5,  12, STAGE(7));
    BODY(6,  12, STAGE(8));
    BODY(7,  12, STAGE(9));
    BODY(8,  12, STAGE(10));
    BODY(9,  12, STAGE(11));
    BODY(10, 12, STAGE(12));
    BODY(11, 12, STAGE(13));
    BODY(12, 12, STAGE(14));
    BODY(13, 12, STAGE(15));
    BODY(14, 8,  (void)0);
    BODY(15, 4,  (void)0);
}

extern "C" void kernel_launch(void* const* d_in, const int* in_sizes, int n_in,
                              void* d_out, int out_size, void* d_ws, size_t ws_size,
                              hipStream_t stream) {
    const float* obs   = (const float*)d_in[0];
    const float* rnn   = (const float*)d_in[1];
    const int*   alive = (const int*)d_in[2];
    const float* W     = (const float*)d_in[3];
    const float* bias  = (const float*)d_in[4];
    float* out = (float*)d_out;
    (void)in_sizes; (void)n_in; (void)d_ws; (void)ws_size; (void)out_size;

    commnet_fused<<<2048, 256, 0, stream>>>(obs, rnn, alive, W, bias, out);
}

// Round 11
// 135.856 us; speedup vs baseline: 1.0910x; 1.0910x over previous
//
#include <hip/hip_runtime.h>
#include <hip/hip_bf16.h>

// Problem constants: A=8 agents, B=64 envs, S=1024 seq, H=128 hidden.
#define AN 8
#define BN 64
#define SN 1024
#define HN 128
// rows M = A*B*S = 524288, strips of 16 rows = 32768 strips
#define NSTRIPS ((AN * BN * SN) / 16)
#define SP 132   // stripbuf row pitch (floats): 528B rows, 16B-aligned, bank-rotating

typedef __attribute__((ext_vector_type(8))) short bf16x8;
typedef __attribute__((ext_vector_type(4))) float f32x4;

__device__ __forceinline__ short f2bf(float f) {
    unsigned u = __builtin_bit_cast(unsigned, f);
    // round-to-nearest-even to bf16
    unsigned r = (u + 0x7fffu + ((u >> 16) & 1u)) >> 16;
    return (short)r;
}

__global__ __launch_bounds__(256) void commnet_fused(
    const float* __restrict__ obs,   // (A*B, S, H)
    const float* __restrict__ rnn,   // (S, B, A, H)
    const int*   __restrict__ alive, // (A, B, S, 1)
    const float* __restrict__ W,     // (H, H) [out, in]
    const float* __restrict__ bias,  // (H,)
    float* __restrict__ out)         // (A*B, S, H)
{
    // Pre-packed B fragments in LDS: B[k][n] = W[n][k], bf16.
    // Fragment (nt, ks): lane l holds B[32*ks + 8*(l>>4) + j][16*nt + (l&15)]
    __shared__ bf16x8 Bfrag[8][4][64];      // 32 KiB
    __shared__ float  stripbuf[4][16 * SP]; // 33 KiB: per-wave 16x128 out tile

    const int tid  = threadIdx.x;
    const int lane = tid & 63;
    const int wv   = tid >> 6;

    for (int e = tid; e < 8 * 4 * 64; e += 256) {
        int l  = e & 63;
        int ks = (e >> 6) & 3;
        int nt = e >> 8;
        int col = 16 * nt + (l & 15);      // n index (W row)
        int k0  = 32 * ks + 8 * (l >> 4);  // k index (W col)
        const float* wp = W + col * HN + k0;
        float4 w0 = *(const float4*)(wp);
        float4 w1 = *(const float4*)(wp + 4);
        bf16x8 f;
        f[0] = f2bf(w0.x); f[1] = f2bf(w0.y); f[2] = f2bf(w0.z); f[3] = f2bf(w0.w);
        f[4] = f2bf(w1.x); f[5] = f2bf(w1.y); f[6] = f2bf(w1.z); f[7] = f2bf(w1.w);
        Bfrag[nt][ks][l] = f;
    }
    __syncthreads();

    const int r  = lane & 15;  // A-row within strip / D-col within 16-tile
    const int kg = lane >> 4;  // k-group (A) / row-group (D)

    // Epilogue lane geometry: column block is loop-invariant.
    const int ecol = 4 * (lane & 31);          // 0..124
    const int erow = lane >> 5;                // 0/1 (row parity within pair)
    const float4 bv = *(const float4*)(bias + ecol);  // bias for lane's 4 cols

    for (int strip = blockIdx.x * 4 + wv; strip < NSTRIPS; strip += gridDim.x * 4) {
        const int ab = strip >> 6;            // 64 strips per (a,b)
        const int s0 = (strip & 63) << 4;
        const int a  = ab >> 6;
        const int b  = ab & 63;
        const int s_r = s0 + r;

        // alive scale for this lane's A-row: alive[a,b,s] / max(sum_a' alive, 1)
        int asum = 0, mya = 0;
#pragma unroll
        for (int a2 = 0; a2 < AN; ++a2) {
            int v = alive[(a2 * BN + b) * SN + s_r];
            asum += v;
            if (a2 == a) mya = v;
        }

        // rnn row -> bf16 fragments; DEAD ROWS SKIP THE LOADS ENTIRELY
        // (exec-masked: inactive lanes issue no requests -> ~50% of rnn
        // traffic eliminated). msg row = 0 for dead rows, matching ref.
        bf16x8 mb[4];
        if (mya) {
            const float scale = 1.0f / (float)(asum < 1 ? 1 : asum);
            const float* arow = rnn + ((size_t)s_r * BN + b) * (AN * HN) + a * HN;
#pragma unroll
            for (int ks = 0; ks < 4; ++ks) {
                const int k0 = 32 * ks + 8 * kg;
                float4 a0 = *(const float4*)(arow + k0);
                float4 a1 = *(const float4*)(arow + k0 + 4);
                mb[ks][0] = f2bf(a0.x * scale); mb[ks][1] = f2bf(a0.y * scale);
                mb[ks][2] = f2bf(a0.z * scale); mb[ks][3] = f2bf(a0.w * scale);
                mb[ks][4] = f2bf(a1.x * scale); mb[ks][5] = f2bf(a1.y * scale);
                mb[ks][6] = f2bf(a1.z * scale); mb[ks][7] = f2bf(a1.w * scale);
            }
        } else {
#pragma unroll
            for (int ks = 0; ks < 4; ++ks)
                mb[ks] = (bf16x8){0, 0, 0, 0, 0, 0, 0, 0};
        }

        f32x4 acc[8];
#pragma unroll
        for (int nt = 0; nt < 8; ++nt) acc[nt] = (f32x4){0.f, 0.f, 0.f, 0.f};
#pragma unroll
        for (int ks = 0; ks < 4; ++ks) {
#pragma unroll
            for (int nt = 0; nt < 8; ++nt)
                acc[nt] = __builtin_amdgcn_mfma_f32_16x16x32_bf16(
                    mb[ks], Bfrag[nt][ks][lane], acc[nt], 0, 0, 0);
        }

        // Stage result in per-wave LDS tile: D[row=4*kg+rg][col=16*nt+r].
        float* sb = stripbuf[wv];
#pragma unroll
        for (int nt = 0; nt < 8; ++nt) {
            const int col = 16 * nt + r;
#pragma unroll
            for (int rg = 0; rg < 4; ++rg)
                sb[(4 * kg + rg) * SP + col] = acc[nt][rg];
        }

        // Lane-linear read-back -> full-line NT stores (1KB contiguous per
        // instruction: two whole 512B output rows). obs read matches.
        const size_t outbase = (size_t)ab * (SN * HN) + (size_t)s0 * HN;
#pragma unroll
        for (int i = 0; i < 8; ++i) {
            const int row = 2 * i + erow;
            f32x4 v = *(const f32x4*)&sb[row * SP + ecol];
            const size_t idx = outbase + (size_t)row * HN + ecol;
            float4 o = *(const float4*)(obs + idx);
            float4 res;
            res.x = v[0] + bv.x + o.x;
            res.y = v[1] + bv.y + o.y;
            res.z = v[2] + bv.z + o.z;
            res.w = v[3] + bv.w + o.w;
            __builtin_nontemporal_store(res.x, out + idx);
            __builtin_nontemporal_store(res.y, out + idx + 1);
            __builtin_nontemporal_store(res.z, out + idx + 2);
            __builtin_nontemporal_store(res.w, out + idx + 3);
        }
    }
}

extern "C" void kernel_launch(void* const* d_in, const int* in_sizes, int n_in,
                              void* d_out, int out_size, void* d_ws, size_t ws_size,
                              hipStream_t stream) {
    const float* obs   = (const float*)d_in[0];
    const float* rnn   = (const float*)d_in[1];
    const int*   alive = (const int*)d_in[2];
    const float* W     = (const float*)d_in[3];
    const float* bias  = (const float*)d_in[4];
    float* out = (float*)d_out;
    (void)in_sizes; (void)n_in; (void)d_ws; (void)ws_size; (void)out_size;

    commnet_fused<<<2048, 256, 0, stream>>>(obs, rnn, alive, W, bias, out);
}